// Round 10
// baseline (4556.995 us; speedup 1.0000x reference)
//
#include <hip/hip_runtime.h>
#include <math.h>

#define BB 128
#define TT 1024
#define II 256
#define HH 512
#define KK 768

typedef __attribute__((ext_vector_type(8))) short short8v;
typedef __attribute__((ext_vector_type(4))) float float4v;
typedef __attribute__((ext_vector_type(4))) unsigned int uint4v;

// ---- workspace layout ----
#define BARS_OFF   0
#define BARS_SZ    32768                 // 8 grp x 16 WG x 64 uints of flags
#define WFRAG_OFF  BARS_SZ
#define WFRAG_SZ   (96 * 24 * 64 * 16)   // bf16 MFMA B-fragments
#define GS_OFF     (WFRAG_OFF + WFRAG_SZ)
#define GS_STRIDE  65536                 // per-group: hFrag 16KB + rhFrag 16KB
#define WS_NEED    ((size_t)GS_OFF + 8 * GS_STRIDE)

#define NT_MAIN 320                      // 4 compute waves + 1 stager wave

__device__ __forceinline__ unsigned short bf16_rne(float f) {
    unsigned u = __builtin_bit_cast(unsigned, f);
    unsigned r = u + 0x7FFFu + ((u >> 16) & 1u);
    return (unsigned short)(r >> 16);
}
__device__ __forceinline__ void cp16(void* lds, const void* g) {
    __builtin_amdgcn_global_load_lds(
        (const __attribute__((address_space(1))) unsigned*)g,
        (__attribute__((address_space(3))) unsigned*)lds, 16, 0, 0);
}
__device__ __forceinline__ float sigmoid_fast(float v) {
    return __builtin_amdgcn_rcpf(1.f + __expf(-v));
}
__device__ __forceinline__ float tanh_fast(float v) {
    const float e = __expf(2.f * v);                    // inf/0 saturate to +-1
    return 1.f - 2.f * __builtin_amdgcn_rcpf(e + 1.f);
}

#define MFMA __builtin_amdgcn_mfma_f32_16x16x32_bf16

// ---- one-time weight repack: fp32 [768][512] -> bf16 MFMA B-fragments ----
// frag(ntAll, kt): lane l, elem j -> W[kt*32 + (l>>4)*8 + j][n0 + (l&15)]
__global__ void repack_w(const float* __restrict__ Wz, const float* __restrict__ Wr,
                         const float* __restrict__ Wh, short8v* __restrict__ wB) {
    const int ntAll = blockIdx.x;
    const int w = threadIdx.x >> 6, l = threadIdx.x & 63;
    const float* W; int n0;
    if (ntAll < 32)      { W = Wz; n0 = ntAll * 16; }
    else if (ntAll < 64) { W = Wr; n0 = (ntAll - 32) * 16; }
    else                 { W = Wh; n0 = (ntAll - 64) * 16; }
    const int n = n0 + (l & 15);
    for (int kt = w; kt < 24; kt += 4) {
        const int k0 = kt * 32 + (l >> 4) * 8;
        short8v f;
        #pragma unroll
        for (int j = 0; j < 8; ++j)
            f[j] = (short)bf16_rne(W[(size_t)(k0 + j) * HH + n]);
        wB[((size_t)ntAll * 24 + kt) * 64 + l] = f;
    }
}

// ---- persistent MFMA GRU (R8 memory semantics, 2 barriers/step) ----
// 128 WGs x 320 thr. group g = bid&7 (16 rows), WG s = bid>>3 owns cols
// [32s,32s+32). Cross-WG state: bf16 A-frags via sc1 dwordx4 (agent-coherent,
// MALL) + per-WG monotonic half-flags (relaxed agent atomics). Producer waves
// publish their own halves (no barrier on the publish path). Flags per WG:
// [0]=h_lo(w0 l0) [8]=h_hi(w1 l32) [16]=rh_lo(w2 l0) [24]=rh_hi(w3 l32).
__global__ __launch_bounds__(NT_MAIN, 1) void gru_mfma(
    const float* __restrict__ x,
    const float* __restrict__ bz, const float* __restrict__ br,
    const float* __restrict__ bh,
    float* __restrict__ out,
    const short8v* __restrict__ wB,
    char* __restrict__ gsBase,
    unsigned* __restrict__ bars)
{
    __shared__ short8v bx1[4][8][64];    // 32KB P1 x-part weights (wave's tile)
    __shared__ short8v bx2[2][8][64];    // 16KB P2 x-part weights
    __shared__ short8v xF[2][8][64];     // 16KB x_t A-frags, double-buffered
    __shared__ float4v red1[4][4][64];   // 16KB P1 partials [tile][wave][lane]
    __shared__ float4v red2[2][4][64];   //  8KB P2 partials
    __shared__ float rhA[16][33];        // r*h staging (local cols)
    __shared__ float hL[16][33];         // fp32 h master (local cols)

    const int tid = threadIdx.x;
    const int w = tid >> 6, l = tid & 63;
    const int g = blockIdx.x & 7, s = blockIdx.x >> 3;
    const int m_ = l & 15, kg = l >> 4;

    char* gs = gsBase + (size_t)g * GS_STRIDE;
    short8v* hFrag  = (short8v*)gs;                  // frag kt=s at +s*64
    short8v* rhFrag = hFrag + 16 * 64;
    unsigned* flagBase = bars + (size_t)g * 16 * 64;

    // ---- weight setup (compute waves) ----
    short8v wh1[4][4];   // P1 h-part  [out tile][k-slot of this wave's quarter]
    short8v wh2[2][4];   // P2 rh-part [hc tile][k-slot]
    if (w < 4) {
        const int ownNt = (w < 2) ? (2 * s + w) : (32 + 2 * s + (w - 2));
        for (int i = 0; i < 8; ++i)
            cp16(&bx1[w][i][0], wB + ((size_t)ownNt * 24 + i) * 64 + l);
        if (w < 2)
            for (int i = 0; i < 8; ++i)
                cp16(&bx2[w][i][0], wB + ((size_t)(64 + 2 * s + w) * 24 + i) * 64 + l);
        #pragma unroll
        for (int T = 0; T < 4; ++T) {
            const int nt = (T < 2) ? (2 * s + T) : (32 + 2 * s + (T - 2));
            #pragma unroll
            for (int q = 0; q < 4; ++q)
                wh1[T][q] = wB[((size_t)nt * 24 + 8 + 4 * w + q) * 64 + l];
        }
        #pragma unroll
        for (int n2 = 0; n2 < 2; ++n2)
            #pragma unroll
            for (int q = 0; q < 4; ++q)
                wh2[n2][q] = wB[((size_t)(64 + 2 * s + n2) * 24 + 8 + 4 * w + q) * 64 + l];
    }
    const float bias1 = (w < 2) ? bz[s * 32 + w * 16 + m_]
                    : (w < 4)  ? br[s * 32 + (w - 2) * 16 + m_] : 0.f;
    const float bias2 = (w < 2) ? bh[s * 32 + w * 16 + m_] : 0.f;

    for (int idx = tid; idx < 16 * 33; idx += NT_MAIN) ((float*)hL)[idx] = 0.f;

    // ---- prologue: stage x(0) into buffer 0 ----
    for (int slot = tid; slot < 512; slot += NT_MAIN) {
        const int kt = slot >> 6, ll = slot & 63;
        const float* xp = x + (size_t)(g * 16 + (ll & 15)) * (TT * II)
                            + kt * 32 + (ll >> 4) * 8;
        const float4 v0 = *(const float4*)xp;
        const float4 v1 = *(const float4*)(xp + 4);
        short8v f;
        f[0] = (short)bf16_rne(v0.x); f[1] = (short)bf16_rne(v0.y);
        f[2] = (short)bf16_rne(v0.z); f[3] = (short)bf16_rne(v0.w);
        f[4] = (short)bf16_rne(v1.x); f[5] = (short)bf16_rne(v1.y);
        f[6] = (short)bf16_rne(v1.z); f[7] = (short)bf16_rne(v1.w);
        xF[0][kt][ll] = f;
    }
    __syncthreads();   // drains cp16 + xF/hL writes

    float4 xv[16];     // wave4's x(t+1) prefetch registers

    for (int t = 0; t < TT; ++t) {
        const int xb = t & 1;

        // ===== phase 1: waves0-3 P1 x-part; wave4 issues x(t+1) loads =====
        float4v ax0 = {0.f, 0.f, 0.f, 0.f}, ax1 = ax0;
        if (w < 4) {
            #pragma unroll
            for (int kt = 0; kt < 8; kt += 2) {
                ax0 = MFMA(xF[xb][kt][l],     bx1[w][kt][l],     ax0, 0, 0, 0);
                ax1 = MFMA(xF[xb][kt + 1][l], bx1[w][kt + 1][l], ax1, 0, 0, 0);
            }
        } else if (t + 1 < TT) {
            #pragma unroll
            for (int i = 0; i < 8; ++i) {
                const float* xp = x + (size_t)(g * 16 + m_) * (TT * II)
                                    + (size_t)(t + 1) * II + i * 32 + kg * 8;
                xv[2 * i]     = *(const float4*)xp;
                xv[2 * i + 1] = *(const float4*)(xp + 4);
            }
        }

        // ===== phase 2: h poll (2 half-flags x 4 producers) + load + MFMA =====
        if (w < 4) {
            if (l < 8) {
                const unsigned* fp = flagBase + (4 * w + (l >> 1)) * 64 + (l & 1) * 8;
                while (__hip_atomic_load(fp, __ATOMIC_RELAXED,
                                         __HIP_MEMORY_SCOPE_AGENT) < (unsigned)t)
                    __builtin_amdgcn_s_sleep(1);
            }
            uint4v u0, u1, u2, u3;
            const short8v* hp = hFrag + (size_t)(4 * w) * 64 + l;
            asm volatile("global_load_dwordx4 %0, %1, off sc1" : "=v"(u0) : "v"(hp)       : "memory");
            asm volatile("global_load_dwordx4 %0, %1, off sc1" : "=v"(u1) : "v"(hp +  64) : "memory");
            asm volatile("global_load_dwordx4 %0, %1, off sc1" : "=v"(u2) : "v"(hp + 128) : "memory");
            asm volatile("global_load_dwordx4 %0, %1, off sc1" : "=v"(u3) : "v"(hp + 192) : "memory");
            asm volatile("s_waitcnt vmcnt(0)" ::: "memory");
            __builtin_amdgcn_sched_barrier(0);
            const short8v hf0 = __builtin_bit_cast(short8v, u0);
            const short8v hf1 = __builtin_bit_cast(short8v, u1);
            const short8v hf2 = __builtin_bit_cast(short8v, u2);
            const short8v hf3 = __builtin_bit_cast(short8v, u3);
            float4v h0 = {0.f,0.f,0.f,0.f}, h1 = h0, h2 = h0, h3 = h0;
            #pragma unroll
            for (int q = 0; q < 4; ++q) {
                const short8v a = (q == 0) ? hf0 : (q == 1) ? hf1 : (q == 2) ? hf2 : hf3;
                h0 = MFMA(a, wh1[0][q], h0, 0, 0, 0);
                h1 = MFMA(a, wh1[1][q], h1, 0, 0, 0);
                h2 = MFMA(a, wh1[2][q], h2, 0, 0, 0);
                h3 = MFMA(a, wh1[3][q], h3, 0, 0, 0);
            }
            red1[0][w][l] = h0; red1[1][w][l] = h1;
            red1[2][w][l] = h2; red1[3][w][l] = h3;
        }
        __syncthreads();   // S1

        // ===== phase 3: reduce + sigmoid; w2/3 publish own rh halves =====
        float zreg[4];
        if (w < 4) {
            float4v s1v = ax0 + ax1 + red1[w][0][l] + red1[w][1][l]
                                  + red1[w][2][l] + red1[w][3][l];
            #pragma unroll
            for (int r = 0; r < 4; ++r) {
                const float sg = sigmoid_fast(s1v[r] + bias1);
                if (w < 2) zreg[r] = sg;
                else rhA[kg * 4 + r][(w - 2) * 16 + m_] =
                         sg * hL[kg * 4 + r][(w - 2) * 16 + m_];
            }
        }
        if (w == 2 || w == 3) {
            asm volatile("s_waitcnt lgkmcnt(0)" ::: "memory");   // own rhA writes done
            __builtin_amdgcn_sched_barrier(0);
            const bool mine = (w == 2) ? (l < 32) : (l >= 32);   // own col half
            if (mine) {
                short8v f;
                #pragma unroll
                for (int j = 0; j < 8; ++j)
                    f[j] = (short)bf16_rne(rhA[m_][kg * 8 + j]);
                const uint4v u = __builtin_bit_cast(uint4v, f);
                short8v* dp = rhFrag + (size_t)s * 64 + l;
                asm volatile("global_store_dwordx4 %0, %1, off sc1" :: "v"(dp), "v"(u) : "memory");
            }
            asm volatile("s_waitcnt vmcnt(0)" ::: "memory");
            if (w == 2 && l == 0)
                __hip_atomic_store(flagBase + s * 64 + 16, (unsigned)(t + 1),
                                   __ATOMIC_RELAXED, __HIP_MEMORY_SCOPE_AGENT);
            if (w == 3 && l == 32)
                __hip_atomic_store(flagBase + s * 64 + 24, (unsigned)(t + 1),
                                   __ATOMIC_RELAXED, __HIP_MEMORY_SCOPE_AGENT);
        }
        if (w == 4) {   // xF(t+1) write + out(t-1) store (hL guarded by S1)
            asm volatile("s_waitcnt vmcnt(0)" ::: "memory");
            if (t + 1 < TT) {
                #pragma unroll
                for (int i = 0; i < 8; ++i) {
                    const float4 v0 = xv[2 * i], v1 = xv[2 * i + 1];
                    short8v f;
                    f[0] = (short)bf16_rne(v0.x); f[1] = (short)bf16_rne(v0.y);
                    f[2] = (short)bf16_rne(v0.z); f[3] = (short)bf16_rne(v0.w);
                    f[4] = (short)bf16_rne(v1.x); f[5] = (short)bf16_rne(v1.y);
                    f[6] = (short)bf16_rne(v1.z); f[7] = (short)bf16_rne(v1.w);
                    xF[xb ^ 1][i][l] = f;
                }
            }
            if (t > 0) {
                float* op = out + (size_t)(g * 16 + m_) * (TT * HH)
                                + (size_t)(t - 1) * HH + s * 32 + kg * 8;
                float4 o0, o1;
                o0.x = hL[m_][kg * 8 + 0]; o0.y = hL[m_][kg * 8 + 1];
                o0.z = hL[m_][kg * 8 + 2]; o0.w = hL[m_][kg * 8 + 3];
                o1.x = hL[m_][kg * 8 + 4]; o1.y = hL[m_][kg * 8 + 5];
                o1.z = hL[m_][kg * 8 + 6]; o1.w = hL[m_][kg * 8 + 7];
                *(float4*)op = o0;
                *(float4*)(op + 4) = o1;
            }
        }

        // ===== phase 4: P2 x-part (waves 0,1) =====
        float4v cx0 = {0.f,0.f,0.f,0.f}, cx1 = cx0;
        if (w < 2) {
            #pragma unroll
            for (int kt = 0; kt < 8; kt += 2) {
                cx0 = MFMA(xF[xb][kt][l],     bx2[w][kt][l],     cx0, 0, 0, 0);
                cx1 = MFMA(xF[xb][kt + 1][l], bx2[w][kt + 1][l], cx1, 0, 0, 0);
            }
        }

        // ===== phase 5: rh poll + load + hc MFMA =====
        if (w < 4) {
            if (l < 8) {
                const unsigned* fp = flagBase + (4 * w + (l >> 1)) * 64 + 16 + (l & 1) * 8;
                while (__hip_atomic_load(fp, __ATOMIC_RELAXED,
                                         __HIP_MEMORY_SCOPE_AGENT) < (unsigned)(t + 1))
                    __builtin_amdgcn_s_sleep(1);
            }
            uint4v u0, u1, u2, u3;
            const short8v* rp = rhFrag + (size_t)(4 * w) * 64 + l;
            asm volatile("global_load_dwordx4 %0, %1, off sc1" : "=v"(u0) : "v"(rp)       : "memory");
            asm volatile("global_load_dwordx4 %0, %1, off sc1" : "=v"(u1) : "v"(rp +  64) : "memory");
            asm volatile("global_load_dwordx4 %0, %1, off sc1" : "=v"(u2) : "v"(rp + 128) : "memory");
            asm volatile("global_load_dwordx4 %0, %1, off sc1" : "=v"(u3) : "v"(rp + 192) : "memory");
            asm volatile("s_waitcnt vmcnt(0)" ::: "memory");
            __builtin_amdgcn_sched_barrier(0);
            const short8v rf0 = __builtin_bit_cast(short8v, u0);
            const short8v rf1 = __builtin_bit_cast(short8v, u1);
            const short8v rf2 = __builtin_bit_cast(short8v, u2);
            const short8v rf3 = __builtin_bit_cast(short8v, u3);
            float4v c0 = {0.f,0.f,0.f,0.f}, c1 = c0;
            #pragma unroll
            for (int q = 0; q < 4; ++q) {
                const short8v a = (q == 0) ? rf0 : (q == 1) ? rf1 : (q == 2) ? rf2 : rf3;
                c0 = MFMA(a, wh2[0][q], c0, 0, 0, 0);
                c1 = MFMA(a, wh2[1][q], c1, 0, 0, 0);
            }
            red2[0][w][l] = c0; red2[1][w][l] = c1;
        }
        __syncthreads();   // S3

        // ===== phase 6: blend; w0/1 publish own h halves =====
        if (w < 2) {
            float4v s2v = cx0 + cx1 + red2[w][0][l] + red2[w][1][l]
                                  + red2[w][2][l] + red2[w][3][l];
            #pragma unroll
            for (int r = 0; r < 4; ++r) {
                const int row = kg * 4 + r;
                const int cl = w * 16 + m_;
                const float hc = tanh_fast(s2v[r] + bias2);
                const float ho = hL[row][cl];
                hL[row][cl] = (1.f - zreg[r]) * ho + zreg[r] * hc;
            }
            asm volatile("s_waitcnt lgkmcnt(0)" ::: "memory");   // own hL writes done
            __builtin_amdgcn_sched_barrier(0);
            const bool mine = (w == 0) ? (l < 32) : (l >= 32);
            if (mine) {
                short8v f;
                #pragma unroll
                for (int j = 0; j < 8; ++j)
                    f[j] = (short)bf16_rne(hL[m_][kg * 8 + j]);
                const uint4v u = __builtin_bit_cast(uint4v, f);
                short8v* dp = hFrag + (size_t)s * 64 + l;
                asm volatile("global_store_dwordx4 %0, %1, off sc1" :: "v"(dp), "v"(u) : "memory");
            }
            asm volatile("s_waitcnt vmcnt(0)" ::: "memory");
            if (w == 0 && l == 0)
                __hip_atomic_store(flagBase + s * 64 + 0, (unsigned)(t + 1),
                                   __ATOMIC_RELAXED, __HIP_MEMORY_SCOPE_AGENT);
            if (w == 1 && l == 32)
                __hip_atomic_store(flagBase + s * 64 + 8, (unsigned)(t + 1),
                                   __ATOMIC_RELAXED, __HIP_MEMORY_SCOPE_AGENT);
        }
    }

    __syncthreads();   // hL(TT-1) complete before final out
    if (w == 4) {
        float* op = out + (size_t)(g * 16 + m_) * (TT * HH)
                        + (size_t)(TT - 1) * HH + s * 32 + kg * 8;
        float4 o0, o1;
        o0.x = hL[m_][kg * 8 + 0]; o0.y = hL[m_][kg * 8 + 1];
        o0.z = hL[m_][kg * 8 + 2]; o0.w = hL[m_][kg * 8 + 3];
        o1.x = hL[m_][kg * 8 + 4]; o1.y = hL[m_][kg * 8 + 5];
        o1.z = hL[m_][kg * 8 + 6]; o1.w = hL[m_][kg * 8 + 7];
        *(float4*)op = o0;
        *(float4*)(op + 4) = o1;
    }
}

// ---------------- fallback (round-3 kernel) if ws too small ----------------
#define NWG_FB 64
#define NTHR_FB 512
__global__ __launch_bounds__(NTHR_FB, 1) void gru_rowsplit(
    const float* __restrict__ x,
    const float* __restrict__ Wz, const float* __restrict__ bz,
    const float* __restrict__ Wr, const float* __restrict__ br,
    const float* __restrict__ Wh, const float* __restrict__ bh,
    float* __restrict__ out)
{
    __shared__ float comb_i [KK][2];
    __shared__ float comb2_i[KK][2];
    __shared__ float z_s[2][HH];
    __shared__ float red1[8][257];
    __shared__ float red2[24][129];

    const int tid  = threadIdx.x;
    const int row0 = blockIdx.x * 2;
    const int kh = tid >> 8;
    const int t1 = tid & 255;
    const int n1 = t1 * 4;
    const float* __restrict__ w1 =
        ((n1 < HH) ? (Wz + n1) : (Wr + (n1 - HH))) + (size_t)(kh * 384) * HH;
    const int kq = tid >> 7;
    const int t2 = tid & 127;
    const int n2 = t2 * 4;
    const float* __restrict__ w2 = Wh + n2 + (size_t)(kq * 192) * HH;

    float b1[4], b2[4];
    #pragma unroll
    for (int j = 0; j < 4; ++j) {
        b1[j] = (n1 + j < HH) ? bz[n1 + j] : br[n1 + j - HH];
        b2[j] = bh[n2 + j];
    }
    for (int idx = tid; idx < HH * 2; idx += NTHR_FB)
        comb_i[II + (idx >> 1)][idx & 1] = 0.f;
    __syncthreads();

    for (int t = 0; t < TT; ++t) {
        {
            const int r = tid >> 8, k = tid & 255;
            const float v = x[(size_t)(row0 + r) * (TT * II) + (size_t)t * II + k];
            comb_i [k][r] = v;
            comb2_i[k][r] = v;
        }
        __syncthreads();
        float a00=0,a01=0,a02=0,a03=0,a10=0,a11=0,a12=0,a13=0;
        {
            const int kb = kh * 384;
            #pragma unroll 8
            for (int k = 0; k < 384; ++k) {
                const float4 w = *(const float4*)(w1 + (size_t)k * HH);
                const float2 a = *(const float2*)&comb_i[kb + k][0];
                a00 += a.x*w.x; a01 += a.x*w.y; a02 += a.x*w.z; a03 += a.x*w.w;
                a10 += a.y*w.x; a11 += a.y*w.y; a12 += a.y*w.z; a13 += a.y*w.w;
            }
        }
        if (kh == 1) {
            red1[0][t1]=a00; red1[1][t1]=a01; red1[2][t1]=a02; red1[3][t1]=a03;
            red1[4][t1]=a10; red1[5][t1]=a11; red1[6][t1]=a12; red1[7][t1]=a13;
        }
        __syncthreads();
        if (kh == 0) {
            float accv[2][4] = {{a00,a01,a02,a03},{a10,a11,a12,a13}};
            #pragma unroll
            for (int r = 0; r < 2; ++r) {
                #pragma unroll
                for (int j = 0; j < 4; ++j) {
                    const int n = n1 + j;
                    const float v = accv[r][j] + red1[r*4+j][t1] + b1[j];
                    const float sg = 1.f / (1.f + __expf(-v));
                    if (n < HH) z_s[r][n] = sg;
                    else {
                        const int nh = n - HH;
                        comb2_i[II + nh][r] = sg * comb_i[II + nh][r];
                    }
                }
            }
        }
        __syncthreads();
        float c00=0,c01=0,c02=0,c03=0,c10=0,c11=0,c12=0,c13=0;
        {
            const int kb = kq * 192;
            #pragma unroll 8
            for (int k = 0; k < 192; ++k) {
                const float4 w = *(const float4*)(w2 + (size_t)k * HH);
                const float2 a = *(const float2*)&comb2_i[kb + k][0];
                c00 += a.x*w.x; c01 += a.x*w.y; c02 += a.x*w.z; c03 += a.x*w.w;
                c10 += a.y*w.x; c11 += a.y*w.y; c12 += a.y*w.z; c13 += a.y*w.w;
            }
        }
        if (kq > 0) {
            const int base = (kq - 1) * 8;
            red2[base+0][t2]=c00; red2[base+1][t2]=c01;
            red2[base+2][t2]=c02; red2[base+3][t2]=c03;
            red2[base+4][t2]=c10; red2[base+5][t2]=c11;
            red2[base+6][t2]=c12; red2[base+7][t2]=c13;
        }
        __syncthreads();
        if (kq == 0) {
            float accv[2][4] = {{c00,c01,c02,c03},{c10,c11,c12,c13}};
            #pragma unroll
            for (int r = 0; r < 2; ++r) {
                float hn4[4];
                #pragma unroll
                for (int j = 0; j < 4; ++j) {
                    const int n = n2 + j;
                    const int jj = r * 4 + j;
                    const float v = accv[r][j] + red2[jj][t2] + red2[8+jj][t2]
                                  + red2[16+jj][t2] + b2[j];
                    const float hc = tanhf(v);
                    const float zv = z_s[r][n];
                    const float ho = comb_i[II + n][r];
                    const float hn = (1.f - zv) * ho + zv * hc;
                    comb_i[II + n][r] = hn;
                    hn4[j] = hn;
                }
                *(float4*)&out[(size_t)(row0 + r) * (TT * HH) + (size_t)t * HH + n2] =
                    make_float4(hn4[0], hn4[1], hn4[2], hn4[3]);
            }
        }
        __syncthreads();
    }
}

extern "C" void kernel_launch(void* const* d_in, const int* in_sizes, int n_in,
                              void* d_out, int out_size, void* d_ws, size_t ws_size,
                              hipStream_t stream) {
    const float* x  = (const float*)d_in[0];
    const float* Wz = (const float*)d_in[1];
    const float* bz = (const float*)d_in[2];
    const float* Wr = (const float*)d_in[3];
    const float* br = (const float*)d_in[4];
    const float* Wh = (const float*)d_in[5];
    const float* bh = (const float*)d_in[6];
    float* out = (float*)d_out;

    if (ws_size < WS_NEED) {
        gru_rowsplit<<<NWG_FB, NTHR_FB, 0, stream>>>(x, Wz, bz, Wr, br, Wh, bh, out);
        return;
    }

    char* ws = (char*)d_ws;
    unsigned* bars = (unsigned*)(ws + BARS_OFF);
    short8v*  wB   = (short8v*)(ws + WFRAG_OFF);
    char*     gs   = ws + GS_OFF;

    hipMemsetAsync(bars, 0, BARS_SZ, stream);
    hipMemsetAsync(gs, 0, 8 * (size_t)GS_STRIDE, stream);   // h0 = 0 frags
    repack_w<<<96, 256, 0, stream>>>(Wz, Wr, Wh, wB);
    gru_mfma<<<128, NT_MAIN, 0, stream>>>(x, bz, br, bh, out, wB, gs, bars);
}